// Round 1
// baseline (276.580 us; speedup 1.0000x reference)
//
#include <hip/hip_runtime.h>

#define DD 64
#define HH 512
#define RT 16     // rows per block
#define TPB 256

__device__ __forceinline__ float fast_tanh(float x) {
    // tanh(x) = 1 - 2/(exp(2x)+1); exact limits at +/-inf, no branches
    float e = __expf(2.0f * x);
    return 1.0f - 2.0f * __builtin_amdgcn_rcpf(e + 1.0f);
}

// Et[b*HH + a] = W2[a,b] * sum_i W1[1+i, a] * W3[b, i]
__global__ __launch_bounds__(TPB, 2) void precompute_Et(
    const float* __restrict__ W1, const float* __restrict__ W2,
    const float* __restrict__ W3, float* __restrict__ Et)
{
    __shared__ float w3b[DD];
    const int b = blockIdx.x;
    const int tid = threadIdx.x;
    if (tid < DD) w3b[tid] = W3[b * DD + tid];
    __syncthreads();
    for (int a = tid; a < HH; a += TPB) {
        float s = 0.0f;
#pragma unroll 8
        for (int i = 0; i < DD; ++i)
            s += W1[(1 + i) * HH + a] * w3b[i];
        Et[b * HH + a] = W2[a * HH + b] * s;
    }
}

__global__ __launch_bounds__(TPB, 2) void cnf_main(
    const float* __restrict__ t,  const float* __restrict__ x,
    const float* __restrict__ W1, const float* __restrict__ b1,
    const float* __restrict__ W2, const float* __restrict__ b2,
    const float* __restrict__ W3, const float* __restrict__ b3,
    const float* __restrict__ Et, float* __restrict__ out)
{
    __shared__ float xs[RT][DD];
    __shared__ float h1s[RT * HH];   // becomes d1 after conversion pass
    __shared__ float h2s[RT * HH];   // becomes d2 after conversion pass
    __shared__ float wred[4][8];

    const int tid = threadIdx.x;
    const int r0 = blockIdx.x * RT;
    const float tt = t[0];

    // ---- load x tile (first 64 of 65 columns) ----
    for (int idx = tid; idx < RT * DD; idx += TPB) {
        int r = idx >> 6, c = idx & 63;
        xs[r][c] = x[(r0 + r) * (DD + 1) + c];
    }
    __syncthreads();

    // ---- phase 1: h1 = tanh([t,x] @ W1 + b1), tile 16x512 ----
    for (int idx = tid; idx < RT * HH; idx += TPB) {
        int r = idx >> 9, a = idx & (HH - 1);
        float z = b1[a] + tt * W1[a];          // W1 row 0 multiplies t
#pragma unroll 8
        for (int j = 0; j < DD; ++j)
            z += xs[r][j] * W1[(1 + j) * HH + a];
        h1s[idx] = fast_tanh(z);
    }
    __syncthreads();

    // thread tiling for phases 2 & 4: 4 cols x 8 rows per thread
    const int q    = tid & 127;    // column quad: cols 4q..4q+3
    const int half = tid >> 7;     // row half (all lanes of a wave share it)
    const int rb   = half * 8;

    // ---- phase 2: h2 = tanh(h1 @ W2 + b2) ----
    {
        float acc[8][4];
#pragma unroll
        for (int r8 = 0; r8 < 8; ++r8)
#pragma unroll
            for (int j = 0; j < 4; ++j) acc[r8][j] = 0.0f;

#pragma unroll 4
        for (int a = 0; a < HH; ++a) {
            const float4 w = *(const float4*)(W2 + a * HH + 4 * q);
#pragma unroll
            for (int r8 = 0; r8 < 8; ++r8) {
                float h = h1s[(rb + r8) * HH + a];   // broadcast read
                acc[r8][0] += h * w.x;
                acc[r8][1] += h * w.y;
                acc[r8][2] += h * w.z;
                acc[r8][3] += h * w.w;
            }
        }
        const float4 bb = *(const float4*)(b2 + 4 * q);
#pragma unroll
        for (int r8 = 0; r8 < 8; ++r8) {
            float4 hv;
            hv.x = fast_tanh(acc[r8][0] + bb.x);
            hv.y = fast_tanh(acc[r8][1] + bb.y);
            hv.z = fast_tanh(acc[r8][2] + bb.z);
            hv.w = fast_tanh(acc[r8][3] + bb.w);
            *(float4*)(h2s + (rb + r8) * HH + 4 * q) = hv;
        }
    }
    __syncthreads();

    // ---- phase 3: dx = h2 @ W3 + b3 -> out cols 0..63 ----
    for (int idx = tid; idx < RT * DD; idx += TPB) {
        int r = idx >> 6, o = idx & 63;
        float s = b3[o];
#pragma unroll 8
        for (int a = 0; a < HH; ++a)
            s += h2s[r * HH + a] * W3[a * DD + o];
        out[(r0 + r) * (DD + 1) + o] = s;
    }
    __syncthreads();

    // ---- phase 3.5: convert h -> d = 1 - h^2 in place ----
    for (int idx = tid; idx < RT * HH; idx += TPB) {
        float v1 = h1s[idx]; h1s[idx] = 1.0f - v1 * v1;
        float v2 = h2s[idx]; h2s[idx] = 1.0f - v2 * v2;
    }
    __syncthreads();

    // ---- phase 4: div[r] = sum_a d1[r,a] * (sum_b Et[b,a] * d2[r,b]) ----
    {
        float vacc[8][4];
#pragma unroll
        for (int r8 = 0; r8 < 8; ++r8)
#pragma unroll
            for (int j = 0; j < 4; ++j) vacc[r8][j] = 0.0f;

#pragma unroll 4
        for (int b = 0; b < HH; ++b) {
            const float4 e = *(const float4*)(Et + b * HH + 4 * q);
#pragma unroll
            for (int r8 = 0; r8 < 8; ++r8) {
                float d2 = h2s[(rb + r8) * HH + b];  // broadcast read (now d2)
                vacc[r8][0] += d2 * e.x;
                vacc[r8][1] += d2 * e.y;
                vacc[r8][2] += d2 * e.z;
                vacc[r8][3] += d2 * e.w;
            }
        }
        float part[8];
#pragma unroll
        for (int r8 = 0; r8 < 8; ++r8) {
            const float4 d1v = *(const float4*)(h1s + (rb + r8) * HH + 4 * q);
            part[r8] = d1v.x * vacc[r8][0] + d1v.y * vacc[r8][1]
                     + d1v.z * vacc[r8][2] + d1v.w * vacc[r8][3];
        }
        // wave reduction over the 64 lanes (which span 64 column-quads)
#pragma unroll
        for (int off = 32; off > 0; off >>= 1)
#pragma unroll
            for (int r8 = 0; r8 < 8; ++r8)
                part[r8] += __shfl_down(part[r8], off);

        const int wave = tid >> 6;
        if ((tid & 63) == 0)
#pragma unroll
            for (int r8 = 0; r8 < 8; ++r8) wred[wave][r8] = part[r8];
    }
    __syncthreads();

    if (tid < RT) {
        int r = tid;
        int w0 = (r < 8) ? 0 : 2;     // waves 0,1 hold rows 0..7; 2,3 hold 8..15
        float dv = wred[w0][r & 7] + wred[w0 + 1][r & 7];
        out[(r0 + r) * (DD + 1) + DD] = dv;
    }
}

extern "C" void kernel_launch(void* const* d_in, const int* in_sizes, int n_in,
                              void* d_out, int out_size, void* d_ws, size_t ws_size,
                              hipStream_t stream) {
    const float* t  = (const float*)d_in[0];
    const float* x  = (const float*)d_in[1];
    const float* W1 = (const float*)d_in[2];
    const float* b1 = (const float*)d_in[3];
    const float* W2 = (const float*)d_in[4];
    const float* b2 = (const float*)d_in[5];
    const float* W3 = (const float*)d_in[6];
    const float* b3 = (const float*)d_in[7];
    float* out = (float*)d_out;
    float* Et  = (float*)d_ws;   // HH*HH floats = 1 MB

    precompute_Et<<<HH, TPB, 0, stream>>>(W1, W2, W3, Et);
    cnf_main<<<8192 / RT, TPB, 0, stream>>>(t, x, W1, b1, W2, b2, W3, b3, Et, out);
}

// Round 2
// 123.596 us; speedup vs baseline: 2.2378x; 2.2378x over previous
//
#include <hip/hip_runtime.h>

#define HH 512
#define DD 64
#define MROWS 32          // rows per block
#define TPB 512           // 8 waves
#define LP (HH + 8)       // LDS row pitch for h1s/h2s (1040 B, 16B-aligned, even bank spread)
#define XP (DD + 8)       // LDS row pitch for xs (144 B, 16B-aligned)

typedef unsigned short u16;
typedef short s16x8 __attribute__((ext_vector_type(8)));   // 8 bf16 = 4 VGPRs (guide §3)
typedef float f32x4 __attribute__((ext_vector_type(4)));

#define MFMA16(A, B, C) __builtin_amdgcn_mfma_f32_16x16x32_bf16((A), (B), (C), 0, 0, 0)

__device__ __forceinline__ u16 f2bf(float f) {        // RNE float->bf16 (finite inputs)
    unsigned u = __builtin_bit_cast(unsigned, f);
    u += 0x7fffu + ((u >> 16) & 1u);
    return (u16)(u >> 16);
}
__device__ __forceinline__ float bf2f(u16 h) {
    return __builtin_bit_cast(float, (unsigned)h << 16);
}
__device__ __forceinline__ float fast_tanh(float x) {
    float e = __expf(2.0f * x);
    return 1.0f - 2.0f * __builtin_amdgcn_rcpf(e + 1.0f);
}

// ws layout:
//   Ett  bf16 [HH][HH]   Ett[a*HH+b] = W2[a][b] * G[a][b]        (B-op for phase 4, n=a major)
//   W2t  bf16 [HH][HH]   W2t[n*HH+k] = W2[k][n]                  (B-op for phase 2)
//   W1t  bf16 [HH][DD]   W1t[n*DD+k] = W1[1+k][n]                (B-op for phase 1)
//   W3t  bf16 [DD][HH]   W3t[o*HH+b] = W3[b][o]                  (B-op for phase 3)
//   z0   f32  [HH]       b1[n] + t*W1[0][n]
#define WS_W2T (HH * HH)
#define WS_W1T (2 * HH * HH)
#define WS_W3T (2 * HH * HH + HH * DD)
#define WS_Z0B ((2 * HH * HH + 2 * HH * DD) * 2)   // byte offset of z0

__global__ __launch_bounds__(256) void precompute(
    const float* __restrict__ t,  const float* __restrict__ W1,
    const float* __restrict__ b1, const float* __restrict__ W2,
    const float* __restrict__ W3, u16* __restrict__ ws16, float* __restrict__ z0)
{
    __shared__ float w1col[DD];
    u16* Ett = ws16;
    u16* W2t = ws16 + WS_W2T;
    u16* W1t = ws16 + WS_W1T;
    u16* W3t = ws16 + WS_W3T;

    const int a = blockIdx.x;       // hidden index 0..511
    const int tid = threadIdx.x;
    if (tid < DD) w1col[tid] = W1[(1 + tid) * HH + a];
    if (tid == 0) z0[a] = b1[a] + t[0] * W1[a];
    __syncthreads();

    if (tid < DD) W1t[a * DD + tid] = f2bf(w1col[tid]);
    if (tid >= 64 && tid < 64 + DD) {
        int o = tid - 64;
        W3t[o * HH + a] = f2bf(W3[a * DD + o]);
    }
    for (int k = tid; k < HH; k += 256)
        W2t[a * HH + k] = f2bf(W2[k * HH + a]);
    for (int b = tid; b < HH; b += 256) {
        float s = 0.0f;
#pragma unroll
        for (int i = 0; i < DD; ++i) s += w1col[i] * W3[b * DD + i];
        Ett[a * HH + b] = f2bf(W2[a * HH + b] * s);
    }
}

__global__ __launch_bounds__(TPB) void cnf_main(
    const float* __restrict__ x,  const u16* __restrict__ ws16,
    const float* __restrict__ z0, const float* __restrict__ b2,
    const float* __restrict__ b3, float* __restrict__ out)
{
    __shared__ u16 h1s[MROWS * LP];     // h1 (bf16), later read as d1 source
    __shared__ u16 h2s[MROWS * LP];     // h2 (bf16), overwritten with d2 in place
    __shared__ u16 xs [MROWS * XP];
    __shared__ float z0s[HH];
    __shared__ float b2s[HH];
    __shared__ float b3s[DD];
    __shared__ float divacc[8][MROWS];

    const u16* Ett = ws16;
    const u16* W2t = ws16 + WS_W2T;
    const u16* W1t = ws16 + WS_W1T;
    const u16* W3t = ws16 + WS_W3T;

    const int tid  = threadIdx.x;
    const int lane = tid & 63;
    const int w    = tid >> 6;      // wave 0..7
    const int q    = lane >> 4;     // quad 0..3
    const int m16  = lane & 15;
    const int kq   = 8 * q;         // frag k offset
    const int n1   = w * 64;        // this wave's 64-col slice (phases 1,2,4)
    const int r0   = blockIdx.x * MROWS;

    // ---- stage: x tile (bf16), z0, b2, b3 ----
    for (int idx = tid; idx < MROWS * DD; idx += TPB) {
        int r = idx >> 6, c = idx & 63;
        xs[r * XP + c] = f2bf(x[(r0 + r) * (DD + 1) + c]);
    }
    if (tid < HH) { z0s[tid] = z0[tid]; b2s[tid] = b2[tid]; }
    if (tid < DD) b3s[tid] = b3[tid];
    __syncthreads();

    // ---- phase 1: h1 = tanh([t,x]@W1 + b1) ; K=64 (t folded into z0) ----
    {
        s16x8 xa00 = *(const s16x8*)(xs + m16 * XP + kq);
        s16x8 xa01 = *(const s16x8*)(xs + m16 * XP + 32 + kq);
        s16x8 xa10 = *(const s16x8*)(xs + (16 + m16) * XP + kq);
        s16x8 xa11 = *(const s16x8*)(xs + (16 + m16) * XP + 32 + kq);
#pragma unroll
        for (int ct = 0; ct < 4; ++ct) {
            const u16* bb = W1t + (n1 + ct * 16 + m16) * DD + kq;
            s16x8 bw0 = *(const s16x8*)(bb);
            s16x8 bw1 = *(const s16x8*)(bb + 32);
            f32x4 a0 = {0.f, 0.f, 0.f, 0.f};
            f32x4 a1 = {0.f, 0.f, 0.f, 0.f};
            a0 = MFMA16(xa00, bw0, a0);  a0 = MFMA16(xa01, bw1, a0);
            a1 = MFMA16(xa10, bw0, a1);  a1 = MFMA16(xa11, bw1, a1);
            int col = n1 + ct * 16 + m16;
#pragma unroll
            for (int i = 0; i < 4; ++i) {
                int row = 4 * q + i;
                h1s[row * LP + col]        = f2bf(fast_tanh(a0[i] + z0s[col]));
                h1s[(16 + row) * LP + col] = f2bf(fast_tanh(a1[i] + z0s[col]));
            }
        }
    }
    __syncthreads();

    // ---- phase 2: h2 = tanh(h1@W2 + b2) ; K=512 ----
    {
        f32x4 acc[2][4];
#pragma unroll
        for (int rt = 0; rt < 2; ++rt)
#pragma unroll
            for (int ct = 0; ct < 4; ++ct) acc[rt][ct] = f32x4{0.f, 0.f, 0.f, 0.f};

        const u16* a0p = h1s + m16 * LP + kq;
        const u16* a1p = h1s + (16 + m16) * LP + kq;
        const u16* bp  = W2t + (n1 + m16) * HH + kq;
#pragma unroll 2
        for (int ks = 0; ks < 16; ++ks) {
            s16x8 af0 = *(const s16x8*)(a0p + ks * 32);
            s16x8 af1 = *(const s16x8*)(a1p + ks * 32);
#pragma unroll
            for (int ct = 0; ct < 4; ++ct) {
                s16x8 bw = *(const s16x8*)(bp + ct * (16 * HH) + ks * 32);
                acc[0][ct] = MFMA16(af0, bw, acc[0][ct]);
                acc[1][ct] = MFMA16(af1, bw, acc[1][ct]);
            }
        }
#pragma unroll
        for (int rt = 0; rt < 2; ++rt)
#pragma unroll
            for (int ct = 0; ct < 4; ++ct) {
                int col = n1 + ct * 16 + m16;
#pragma unroll
                for (int i = 0; i < 4; ++i) {
                    int row = rt * 16 + 4 * q + i;
                    h2s[row * LP + col] = f2bf(fast_tanh(acc[rt][ct][i] + b2s[col]));
                }
            }
    }
    __syncthreads();

    // ---- phase 3: dx = h2@W3 + b3 -> out cols 0..63 ; wave = (colTile, rowTile) ----
    {
        const int c   = w & 3;
        const int rb3 = (w >> 2) * 16;
        const int o   = c * 16 + m16;
        f32x4 aA = {0.f, 0.f, 0.f, 0.f};
        f32x4 aB = {0.f, 0.f, 0.f, 0.f};
        const u16* ap = h2s + (rb3 + m16) * LP + kq;
        const u16* bp = W3t + o * HH + kq;
#pragma unroll 2
        for (int ks = 0; ks < 16; ks += 2) {
            aA = MFMA16(*(const s16x8*)(ap + ks * 32),       *(const s16x8*)(bp + ks * 32),       aA);
            aB = MFMA16(*(const s16x8*)(ap + (ks + 1) * 32), *(const s16x8*)(bp + (ks + 1) * 32), aB);
        }
        f32x4 a3 = aA + aB;
#pragma unroll
        for (int i = 0; i < 4; ++i) {
            int row = rb3 + 4 * q + i;
            out[(r0 + row) * (DD + 1) + o] = a3[i] + b3s[o];
        }
    }
    __syncthreads();   // phase 3 done reading h2s

    // ---- phase 3.5: h2s -> d2 = 1 - h2^2, in place ----
    for (int idx = tid; idx < MROWS * HH; idx += TPB) {
        int row = idx >> 9, col = idx & (HH - 1);
        float v = bf2f(h2s[row * LP + col]);
        h2s[row * LP + col] = f2bf(1.0f - v * v);
    }
    __syncthreads();

    // ---- phase 4: M = d2@Ett ; div[r] = sum_col d1[r,col]*M[r,col] ----
    {
        f32x4 acc[2][4];
#pragma unroll
        for (int rt = 0; rt < 2; ++rt)
#pragma unroll
            for (int ct = 0; ct < 4; ++ct) acc[rt][ct] = f32x4{0.f, 0.f, 0.f, 0.f};

        const u16* a0p = h2s + m16 * LP + kq;         // d2 rows 0..15
        const u16* a1p = h2s + (16 + m16) * LP + kq;  // d2 rows 16..31
        const u16* bp  = Ett + (n1 + m16) * HH + kq;
#pragma unroll 2
        for (int ks = 0; ks < 16; ++ks) {
            s16x8 af0 = *(const s16x8*)(a0p + ks * 32);
            s16x8 af1 = *(const s16x8*)(a1p + ks * 32);
#pragma unroll
            for (int ct = 0; ct < 4; ++ct) {
                s16x8 bw = *(const s16x8*)(bp + ct * (16 * HH) + ks * 32);
                acc[0][ct] = MFMA16(af0, bw, acc[0][ct]);
                acc[1][ct] = MFMA16(af1, bw, acc[1][ct]);
            }
        }
        float part[2][4];
#pragma unroll
        for (int rt = 0; rt < 2; ++rt)
#pragma unroll
            for (int i = 0; i < 4; ++i) part[rt][i] = 0.0f;

#pragma unroll
        for (int rt = 0; rt < 2; ++rt)
#pragma unroll
            for (int ct = 0; ct < 4; ++ct) {
                int col = n1 + ct * 16 + m16;
#pragma unroll
                for (int i = 0; i < 4; ++i) {
                    int row = rt * 16 + 4 * q + i;
                    float h1v = bf2f(h1s[row * LP + col]);
                    part[rt][i] += (1.0f - h1v * h1v) * acc[rt][ct][i];
                }
            }
        // reduce over the 16 lanes (m16) sharing each row
#pragma unroll
        for (int rt = 0; rt < 2; ++rt)
#pragma unroll
            for (int i = 0; i < 4; ++i) {
                float v = part[rt][i];
                v += __shfl_xor(v, 1, 64);
                v += __shfl_xor(v, 2, 64);
                v += __shfl_xor(v, 4, 64);
                v += __shfl_xor(v, 8, 64);
                if (m16 == 0) divacc[w][rt * 16 + 4 * q + i] = v;
            }
    }
    __syncthreads();

    if (tid < MROWS) {
        float s = 0.0f;
#pragma unroll
        for (int ww = 0; ww < 8; ++ww) s += divacc[ww][tid];
        out[(r0 + tid) * (DD + 1) + DD] = s;
    }
}

extern "C" void kernel_launch(void* const* d_in, const int* in_sizes, int n_in,
                              void* d_out, int out_size, void* d_ws, size_t ws_size,
                              hipStream_t stream) {
    const float* t  = (const float*)d_in[0];
    const float* x  = (const float*)d_in[1];
    const float* W1 = (const float*)d_in[2];
    const float* b1 = (const float*)d_in[3];
    const float* W2 = (const float*)d_in[4];
    const float* b2 = (const float*)d_in[5];
    const float* W3 = (const float*)d_in[6];
    const float* b3 = (const float*)d_in[7];
    float* out = (float*)d_out;

    u16*   ws16 = (u16*)d_ws;
    float* z0   = (float*)((char*)d_ws + WS_Z0B);

    precompute<<<HH, 256, 0, stream>>>(t, W1, b1, W2, W3, ws16, z0);
    cnf_main<<<8192 / MROWS, TPB, 0, stream>>>(x, ws16, z0, b2, b3, out);
}

// Round 3
// 97.949 us; speedup vs baseline: 2.8237x; 1.2618x over previous
//
#include <hip/hip_runtime.h>

#define HH 512
#define DD 64
#define MROWS 32
#define TPB 1024
#define LP 520            // u16 pitch for 32x512 LDS tiles

typedef unsigned short u16;
typedef short s16x8 __attribute__((ext_vector_type(8)));   // 8 bf16 = 4 VGPRs
typedef float f32x4 __attribute__((ext_vector_type(4)));

#define MFMA16(A,B,C) __builtin_amdgcn_mfma_f32_16x16x32_bf16((A),(B),(C),0,0,0)

// ---- workspace layout (u16 element offsets) ----
// Ef  [512x512] phase-4 B frags (n=a, k=b), fragment-linear
// W2f [512x512] phase-2 B frags (n, k), fragment-linear
// W1f [512x64]  phase-1 B frags, fragment-linear
// W3f [64x512]  phase-3 B frags, fragment-linear
// fragment-linear addr: ntile*16*K + ks*512 + lane*8  (lane&15 = n, lane>>4 = k-quad)
#define OFF_EF   0
#define OFF_W2F  (HH*HH)
#define OFF_W1F  (2*HH*HH)
#define OFF_W3F  (2*HH*HH + HH*DD)
#define OFF_Z0B  ((2*HH*HH + 2*HH*DD)*2)   // byte offset of z0 (f32[512])

__device__ __forceinline__ u16 f2bf(float f) {
    unsigned u = __builtin_bit_cast(unsigned, f);
    u += 0x7fffu + ((u >> 16) & 1u);
    return (u16)(u >> 16);
}
__device__ __forceinline__ float bf2f(u16 h) {
    return __builtin_bit_cast(float, (unsigned)h << 16);
}
__device__ __forceinline__ float fast_tanh(float x) {
    float e = __expf(2.0f * x);
    return 1.0f - 2.0f * __builtin_amdgcn_rcpf(e + 1.0f);
}

// =======================================================================
// precompute: 37 blocks x 256 threads
//  blocks 0..31 : ntile nt — G row-tile via MFMA (hi/lo split), Ef, W2f, W1f
//  blocks 32..35: W3f o-tile
//  block  36    : z0
// =======================================================================
__global__ __launch_bounds__(256) void precompute(
    const float* __restrict__ t,  const float* __restrict__ W1,
    const float* __restrict__ b1, const float* __restrict__ W2,
    const float* __restrict__ W3, u16* __restrict__ ws16, float* __restrict__ z0)
{
    __shared__ float GL[16 * 520];
    u16* Ef  = ws16 + OFF_EF;
    u16* W2f = ws16 + OFF_W2F;
    u16* W1f = ws16 + OFF_W1F;
    u16* W3f = ws16 + OFF_W3F;

    const int bid = blockIdx.x, tid = threadIdx.x;

    if (bid < 32) {
        const int nt   = bid;
        const int a0   = nt * 16;
        const int lane = tid & 63, w = tid >> 6;   // 4 waves
        const int m16  = lane & 15, q = lane >> 4;

        // ---- G = W1c^T @ W3^T (16a x 512b), K=64, hi/lo bf16 split ----
        s16x8 afh[2], afl[2];
#pragma unroll
        for (int h = 0; h < 2; ++h) {
#pragma unroll
            for (int j = 0; j < 8; ++j) {
                int i = h * 32 + q * 8 + j;
                float v = W1[(1 + i) * HH + a0 + m16];
                u16 hi = f2bf(v);
                afh[h][j] = (short)hi;
                afl[h][j] = (short)f2bf(v - bf2f(hi));
            }
        }
        for (int bt = 0; bt < 8; ++bt) {           // wave covers b-range w*128
            int b0 = w * 128 + bt * 16;
            s16x8 bfh[2], bfl[2];
#pragma unroll
            for (int h = 0; h < 2; ++h) {
                const float* src = W3 + (b0 + m16) * DD + h * 32 + q * 8;
                float4 p0 = *(const float4*)(src);
                float4 p1 = *(const float4*)(src + 4);
                float vv[8] = {p0.x,p0.y,p0.z,p0.w,p1.x,p1.y,p1.z,p1.w};
#pragma unroll
                for (int j = 0; j < 8; ++j) {
                    u16 hi = f2bf(vv[j]);
                    bfh[h][j] = (short)hi;
                    bfl[h][j] = (short)f2bf(vv[j] - bf2f(hi));
                }
            }
            f32x4 c = {0.f, 0.f, 0.f, 0.f};
#pragma unroll
            for (int h = 0; h < 2; ++h) {
                c = MFMA16(afh[h], bfh[h], c);
                c = MFMA16(afh[h], bfl[h], c);
                c = MFMA16(afl[h], bfh[h], c);
            }
#pragma unroll
            for (int r = 0; r < 4; ++r)
                GL[(4 * q + r) * 520 + b0 + m16] = c[r];
        }
        __syncthreads();

        // ---- Ef: Ef(n=a, k=b) = W2[a][b] * G[a][b], fragment-linear ----
        for (int p = 0; p < 4; ++p) {
            int ks = p * 4 + (tid >> 6);
            int ln = tid & 63;
            int al = ln & 15;
            int bq = ks * 32 + (ln >> 4) * 8;
            const float* w2p = W2 + (a0 + al) * HH + bq;
            const float* glp = GL + al * 520 + bq;
            float4 wa = *(const float4*)(w2p), wb = *(const float4*)(w2p + 4);
            float4 ga = *(const float4*)(glp), gb = *(const float4*)(glp + 4);
            s16x8 o;
            o[0]=(short)f2bf(wa.x*ga.x); o[1]=(short)f2bf(wa.y*ga.y);
            o[2]=(short)f2bf(wa.z*ga.z); o[3]=(short)f2bf(wa.w*ga.w);
            o[4]=(short)f2bf(wb.x*gb.x); o[5]=(short)f2bf(wb.y*gb.y);
            o[6]=(short)f2bf(wb.z*gb.z); o[7]=(short)f2bf(wb.w*gb.w);
            *(s16x8*)(Ef + nt * 8192 + ks * 512 + ln * 8) = o;
        }
        // ---- W2f: value(n,k) = W2[k][n] ----
        for (int p = 0; p < 4; ++p) {
            int ks = p * 4 + (tid >> 6);
            int ln = tid & 63;
            int n  = nt * 16 + (ln & 15);
            int k0 = ks * 32 + (ln >> 4) * 8;
            s16x8 o;
#pragma unroll
            for (int j = 0; j < 8; ++j) o[j] = (short)f2bf(W2[(k0 + j) * HH + n]);
            *(s16x8*)(W2f + nt * 8192 + ks * 512 + ln * 8) = o;
        }
        // ---- W1f: value(n,k) = W1[1+k][n], K=64 ----
        if (tid < 128) {
            int ks = tid >> 6, ln = tid & 63;
            int n  = nt * 16 + (ln & 15);
            int k0 = ks * 32 + (ln >> 4) * 8;
            s16x8 o;
#pragma unroll
            for (int j = 0; j < 8; ++j) o[j] = (short)f2bf(W1[(1 + k0 + j) * HH + n]);
            *(s16x8*)(W1f + nt * 1024 + ks * 512 + ln * 8) = o;
        }
    } else if (bid < 36) {
        // ---- W3f: value(n=o, k=b) = W3[b][o] ----
        int ot = bid - 32;
        for (int p = 0; p < 4; ++p) {
            int ks = p * 4 + (tid >> 6);
            int ln = tid & 63;
            int o  = ot * 16 + (ln & 15);
            int k0 = ks * 32 + (ln >> 4) * 8;
            s16x8 v;
#pragma unroll
            for (int j = 0; j < 8; ++j) v[j] = (short)f2bf(W3[(k0 + j) * DD + o]);
            *(s16x8*)(W3f + ot * 8192 + ks * 512 + ln * 8) = v;
        }
    } else {
        for (int n = tid; n < HH; n += 256)
            z0[n] = b1[n] + t[0] * W1[n];
    }
}

// =======================================================================
// cnf_main: 256 blocks x 1024 threads (16 waves, 4/SIMD)
// =======================================================================
__global__ __launch_bounds__(TPB) void cnf_main(
    const float* __restrict__ x,  const u16* __restrict__ ws16,
    const float* __restrict__ z0, const float* __restrict__ b2,
    const float* __restrict__ b3, float* __restrict__ out)
{
    __shared__ u16 h1s[MROWS * LP];
    __shared__ u16 h2s[MROWS * LP];
    __shared__ u16 d2s[MROWS * LP];     // low 4.6 KB doubles as xs before phase 2
    __shared__ float z0s[HH];
    __shared__ float b2s[HH];
    __shared__ float b3s[DD];
    __shared__ float divacc[16][MROWS];

    const u16* Ef  = ws16 + OFF_EF;
    const u16* W2f = ws16 + OFF_W2F;
    const u16* W1f = ws16 + OFF_W1F;
    const u16* W3f = ws16 + OFF_W3F;

    const int tid  = threadIdx.x;
    const int lane = tid & 63;
    const int w    = tid >> 6;        // 16 waves
    const int m16  = lane & 15;
    const int q    = lane >> 4;
    const int kq   = q * 8;
    const int n1   = w * 32;          // wave's 32-col slice (phases 1,2,4)
    const int r0   = blockIdx.x * MROWS;

    u16* xs = d2s;                    // overlap: xs dead after phase 1

    // ---- stage ----
    for (int idx = tid; idx < MROWS * DD; idx += TPB) {
        int r = idx >> 6, c = idx & 63;
        xs[r * 72 + c] = f2bf(x[(r0 + r) * (DD + 1) + c]);
    }
    if (tid < HH) { z0s[tid] = z0[tid]; b2s[tid] = b2[tid]; }
    if (tid < DD) b3s[tid] = b3[tid];
    __syncthreads();

    float d1reg[2][2][4];             // d1 = 1-h1^2, kept in regs for phase 4

    // ---- phase 1: h1 = tanh([t,x]@W1 + z0), K=64 ----
    {
        s16x8 xa[2][2];
#pragma unroll
        for (int rt = 0; rt < 2; ++rt)
#pragma unroll
            for (int h = 0; h < 2; ++h)
                xa[rt][h] = *(const s16x8*)(xs + (rt * 16 + m16) * 72 + h * 32 + kq);
#pragma unroll
        for (int ct = 0; ct < 2; ++ct) {
            int nt = w * 2 + ct;
            s16x8 bw0 = *(const s16x8*)(W1f + nt * 1024 + lane * 8);
            s16x8 bw1 = *(const s16x8*)(W1f + nt * 1024 + 512 + lane * 8);
            int col = n1 + ct * 16 + m16;
#pragma unroll
            for (int rt = 0; rt < 2; ++rt) {
                f32x4 c = {0.f, 0.f, 0.f, 0.f};
                c = MFMA16(xa[rt][0], bw0, c);
                c = MFMA16(xa[rt][1], bw1, c);
#pragma unroll
                for (int i = 0; i < 4; ++i) {
                    float hv = fast_tanh(c[i] + z0s[col]);
                    h1s[(rt * 16 + 4 * q + i) * LP + col] = f2bf(hv);
                    d1reg[rt][ct][i] = 1.0f - hv * hv;
                }
            }
        }
    }
    __syncthreads();

    // ---- phase 2: h2 = tanh(h1@W2 + b2); also d2 = 1-h2^2 -> d2s ----
    {
        f32x4 a00={0,0,0,0}, a01={0,0,0,0}, a10={0,0,0,0}, a11={0,0,0,0};
        const u16* ap0 = h1s + m16 * LP + kq;
        const u16* ap1 = h1s + (16 + m16) * LP + kq;
        const u16* bp0 = W2f + (2 * w + 0) * 8192 + lane * 8;
        const u16* bp1 = W2f + (2 * w + 1) * 8192 + lane * 8;
        s16x8 bA0 = *(const s16x8*)(bp0);
        s16x8 bA1 = *(const s16x8*)(bp1);
        s16x8 bB0 = *(const s16x8*)(bp0 + 512);
        s16x8 bB1 = *(const s16x8*)(bp1 + 512);
#pragma unroll 2
        for (int ks = 0; ks < 16; ks += 2) {
            int k2 = (ks + 2) & 15, k3 = (ks + 3) & 15;
            s16x8 nA0 = *(const s16x8*)(bp0 + k2 * 512);
            s16x8 nA1 = *(const s16x8*)(bp1 + k2 * 512);
            s16x8 f0  = *(const s16x8*)(ap0 + ks * 32);
            s16x8 f1  = *(const s16x8*)(ap1 + ks * 32);
            a00 = MFMA16(f0, bA0, a00);
            a10 = MFMA16(f1, bA0, a10);
            a01 = MFMA16(f0, bA1, a01);
            a11 = MFMA16(f1, bA1, a11);
            s16x8 nB0 = *(const s16x8*)(bp0 + k3 * 512);
            s16x8 nB1 = *(const s16x8*)(bp1 + k3 * 512);
            s16x8 f2  = *(const s16x8*)(ap0 + ks * 32 + 32);
            s16x8 f3  = *(const s16x8*)(ap1 + ks * 32 + 32);
            a00 = MFMA16(f2, bB0, a00);
            a10 = MFMA16(f3, bB0, a10);
            a01 = MFMA16(f2, bB1, a01);
            a11 = MFMA16(f3, bB1, a11);
            bA0 = nA0; bA1 = nA1; bB0 = nB0; bB1 = nB1;
        }
        f32x4 acc[2][2] = {{a00, a01}, {a10, a11}};
#pragma unroll
        for (int rt = 0; rt < 2; ++rt)
#pragma unroll
            for (int ct = 0; ct < 2; ++ct) {
                int col = n1 + ct * 16 + m16;
#pragma unroll
                for (int i = 0; i < 4; ++i) {
                    int row = rt * 16 + 4 * q + i;
                    float hv = fast_tanh(acc[rt][ct][i] + b2s[col]);
                    h2s[row * LP + col] = f2bf(hv);
                    d2s[row * LP + col] = f2bf(1.0f - hv * hv);
                }
            }
    }
    __syncthreads();

    // ---- phase 3 (waves 0..7 only): dx = h2@W3 + b3 ----
    if (w < 8) {
        const int rowt = w >> 2, ot = w & 3;
        f32x4 c3 = {0.f, 0.f, 0.f, 0.f};
        const u16* ap = h2s + (rowt * 16 + m16) * LP + kq;
        const u16* bp = W3f + ot * 8192 + lane * 8;
#pragma unroll 4
        for (int ks = 0; ks < 16; ++ks)
            c3 = MFMA16(*(const s16x8*)(ap + ks * 32),
                        *(const s16x8*)(bp + ks * 512), c3);
        int o = ot * 16 + m16;
#pragma unroll
        for (int i = 0; i < 4; ++i)
            out[(r0 + rowt * 16 + 4 * q + i) * (DD + 1) + o] = c3[i] + b3s[o];
    }

    // ---- phase 4 (all 16 waves): M = d2@Ef; div = sum d1 .* M ----
    {
        f32x4 a00={0,0,0,0}, a01={0,0,0,0}, a10={0,0,0,0}, a11={0,0,0,0};
        const u16* ap0 = d2s + m16 * LP + kq;
        const u16* ap1 = d2s + (16 + m16) * LP + kq;
        const u16* bp0 = Ef + (2 * w + 0) * 8192 + lane * 8;
        const u16* bp1 = Ef + (2 * w + 1) * 8192 + lane * 8;
        s16x8 bA0 = *(const s16x8*)(bp0);
        s16x8 bA1 = *(const s16x8*)(bp1);
        s16x8 bB0 = *(const s16x8*)(bp0 + 512);
        s16x8 bB1 = *(const s16x8*)(bp1 + 512);
#pragma unroll 2
        for (int ks = 0; ks < 16; ks += 2) {
            int k2 = (ks + 2) & 15, k3 = (ks + 3) & 15;
            s16x8 nA0 = *(const s16x8*)(bp0 + k2 * 512);
            s16x8 nA1 = *(const s16x8*)(bp1 + k2 * 512);
            s16x8 f0  = *(const s16x8*)(ap0 + ks * 32);
            s16x8 f1  = *(const s16x8*)(ap1 + ks * 32);
            a00 = MFMA16(f0, bA0, a00);
            a10 = MFMA16(f1, bA0, a10);
            a01 = MFMA16(f0, bA1, a01);
            a11 = MFMA16(f1, bA1, a11);
            s16x8 nB0 = *(const s16x8*)(bp0 + k3 * 512);
            s16x8 nB1 = *(const s16x8*)(bp1 + k3 * 512);
            s16x8 f2  = *(const s16x8*)(ap0 + ks * 32 + 32);
            s16x8 f3  = *(const s16x8*)(ap1 + ks * 32 + 32);
            a00 = MFMA16(f2, bB0, a00);
            a10 = MFMA16(f3, bB0, a10);
            a01 = MFMA16(f2, bB1, a01);
            a11 = MFMA16(f3, bB1, a11);
            bA0 = nA0; bA1 = nA1; bB0 = nB0; bB1 = nB1;
        }
        f32x4 acc[2][2] = {{a00, a01}, {a10, a11}};
#pragma unroll
        for (int rt = 0; rt < 2; ++rt)
#pragma unroll
            for (int i = 0; i < 4; ++i) {
                float v = d1reg[rt][0][i] * acc[rt][0][i]
                        + d1reg[rt][1][i] * acc[rt][1][i];
                v += __shfl_xor(v, 1, 64);
                v += __shfl_xor(v, 2, 64);
                v += __shfl_xor(v, 4, 64);
                v += __shfl_xor(v, 8, 64);
                if (m16 == 0) divacc[w][rt * 16 + 4 * q + i] = v;
            }
    }
    __syncthreads();

    if (tid < MROWS) {
        float s = 0.0f;
#pragma unroll
        for (int ww = 0; ww < 16; ++ww) s += divacc[ww][tid];
        out[(r0 + tid) * (DD + 1) + DD] = s;
    }
}

extern "C" void kernel_launch(void* const* d_in, const int* in_sizes, int n_in,
                              void* d_out, int out_size, void* d_ws, size_t ws_size,
                              hipStream_t stream) {
    const float* t  = (const float*)d_in[0];
    const float* x  = (const float*)d_in[1];
    const float* W1 = (const float*)d_in[2];
    const float* b1 = (const float*)d_in[3];
    const float* W2 = (const float*)d_in[4];
    const float* b2 = (const float*)d_in[5];
    const float* W3 = (const float*)d_in[6];
    const float* b3 = (const float*)d_in[7];
    float* out = (float*)d_out;

    u16*   ws16 = (u16*)d_ws;
    float* z0   = (float*)((char*)d_ws + OFF_Z0B);

    precompute<<<37, 256, 0, stream>>>(t, W1, b1, W2, W3, ws16, z0);
    cnf_main<<<8192 / MROWS, TPB, 0, stream>>>(x, ws16, z0, b2, b3, out);
}

// Round 4
// 94.943 us; speedup vs baseline: 2.9131x; 1.0317x over previous
//
#include <hip/hip_runtime.h>

#define HH 512
#define DD 64
#define MROWS 32
#define TPB 1024
#define LP 520            // u16 pitch for 32x512 LDS tiles

typedef unsigned short u16;
typedef short s16x8 __attribute__((ext_vector_type(8)));   // 8 bf16 = 4 VGPRs
typedef float f32x4 __attribute__((ext_vector_type(4)));

#define MFMA16(A,B,C) __builtin_amdgcn_mfma_f32_16x16x32_bf16((A),(B),(C),0,0,0)

// ---- workspace layout (u16 element offsets), fragment-linear:
//   addr = ntile*16*K + ks*512 + lane*8 ; value[j] = M[k = ks*32+(lane>>4)*8+j][n = nt*16+(lane&15)]
#define OFF_EF   0
#define OFF_W2F  (HH*HH)
#define OFF_W1F  (2*HH*HH)
#define OFF_W3F  (2*HH*HH + HH*DD)
#define OFF_Z0B  ((2*HH*HH + 2*HH*DD)*2)   // byte offset of z0 (f32[512])

__device__ __forceinline__ u16 f2bf(float f) {
    unsigned u = __builtin_bit_cast(unsigned, f);
    u += 0x7fffu + ((u >> 16) & 1u);
    return (u16)(u >> 16);
}
__device__ __forceinline__ float bf2f(u16 h) {
    return __builtin_bit_cast(float, (unsigned)h << 16);
}
__device__ __forceinline__ float fast_tanh(float x) {
    float e = __expf(2.0f * x);
    return 1.0f - 2.0f * __builtin_amdgcn_rcpf(e + 1.0f);
}

// =======================================================================
// precompute: 137 blocks x 256 threads
//   bid 0..63   : Ef (nt = bid>>1, b-half = bid&1) ; bh==0 also writes W1f
//   bid 64..127 : W2f transpose (nt, k-half) via LDS tile
//   bid 128..135: W3f transpose (ot, k-half) via LDS tile
//   bid 136     : z0
// =======================================================================
__global__ __launch_bounds__(256) void precompute(
    const float* __restrict__ t,  const float* __restrict__ W1,
    const float* __restrict__ b1, const float* __restrict__ W2,
    const float* __restrict__ W3, u16* __restrict__ ws16, float* __restrict__ z0)
{
    __shared__ float T[16 * 264 > 256 * 20 ? 16 * 264 : 256 * 20];  // 20.5 KB
    u16* Ef  = ws16 + OFF_EF;
    u16* W2f = ws16 + OFF_W2F;
    u16* W1f = ws16 + OFF_W1F;
    u16* W3f = ws16 + OFF_W3F;

    const int bid = blockIdx.x, tid = threadIdx.x;
    const int lane = tid & 63, wv = tid >> 6;
    const int m16 = lane & 15, q = lane >> 4;

    if (bid < 64) {
        // ================= Ef blocks =================
        const int nt = bid >> 1, bh = bid & 1;
        const int a0 = nt * 16, b0 = bh * 256;

        // A-frags: W1 columns a0..a0+15, K=64, hi/lo bf16 split
        s16x8 afh[2], afl[2];
#pragma unroll
        for (int h = 0; h < 2; ++h)
#pragma unroll
            for (int j = 0; j < 8; ++j) {
                int i = h * 32 + q * 8 + j;
                float v = W1[(1 + i) * HH + a0 + m16];
                u16 hi = f2bf(v);
                afh[h][j] = (short)hi;
                afl[h][j] = (short)f2bf(v - bf2f(hi));
            }
        // G tile: 16a x 256b ; wave covers 64 b
#pragma unroll
        for (int bt = 0; bt < 4; ++bt) {
            int bl = wv * 64 + bt * 16;          // local b
            s16x8 bfh[2], bfl[2];
#pragma unroll
            for (int h = 0; h < 2; ++h) {
                const float* src = W3 + (b0 + bl + m16) * DD + h * 32 + q * 8;
                float4 p0 = *(const float4*)(src);
                float4 p1 = *(const float4*)(src + 4);
                float vv[8] = {p0.x,p0.y,p0.z,p0.w,p1.x,p1.y,p1.z,p1.w};
#pragma unroll
                for (int j = 0; j < 8; ++j) {
                    u16 hi = f2bf(vv[j]);
                    bfh[h][j] = (short)hi;
                    bfl[h][j] = (short)f2bf(vv[j] - bf2f(hi));
                }
            }
            f32x4 c = {0.f, 0.f, 0.f, 0.f};
#pragma unroll
            for (int h = 0; h < 2; ++h) {
                c = MFMA16(afh[h], bfh[h], c);
                c = MFMA16(afh[h], bfl[h], c);
                c = MFMA16(afl[h], bfh[h], c);
            }
#pragma unroll
            for (int r = 0; r < 4; ++r)
                T[(4 * q + r) * 264 + bl + m16] = c[r];
        }
        __syncthreads();

        // Ef pack: 8 ks_local x 64 lanes over 2 passes
#pragma unroll
        for (int p = 0; p < 2; ++p) {
            int ksl = p * 4 + wv;
            int al  = m16;
            int blc = ksl * 32 + q * 8;
            const float* w2p = W2 + (a0 + al) * HH + b0 + blc;
            float4 wa = *(const float4*)(w2p), wb = *(const float4*)(w2p + 4);
            const float* glp = T + al * 264 + blc;
            s16x8 o;
            o[0]=(short)f2bf(wa.x*glp[0]); o[1]=(short)f2bf(wa.y*glp[1]);
            o[2]=(short)f2bf(wa.z*glp[2]); o[3]=(short)f2bf(wa.w*glp[3]);
            o[4]=(short)f2bf(wb.x*glp[4]); o[5]=(short)f2bf(wb.y*glp[5]);
            o[6]=(short)f2bf(wb.z*glp[6]); o[7]=(short)f2bf(wb.w*glp[7]);
            *(s16x8*)(Ef + nt * 8192 + (b0 / 32 + ksl) * 512 + lane * 8) = o;
        }
        // W1f (only bh==0): K=64 -> 2 ks x 64 lanes
        if (bh == 0 && tid < 128) {
            int ks = tid >> 6, ln = tid & 63;
            int n  = nt * 16 + (ln & 15);
            int k0 = ks * 32 + (ln >> 4) * 8;
            s16x8 o;
#pragma unroll
            for (int j = 0; j < 8; ++j) o[j] = (short)f2bf(W1[(1 + k0 + j) * HH + n]);
            *(s16x8*)(W1f + nt * 1024 + ks * 512 + ln * 8) = o;
        }
    } else if (bid < 128) {
        // ================= W2f transpose blocks =================
        const int nt = (bid - 64) >> 1, kh = (bid - 64) & 1;
        const int n0 = nt * 16, k0 = kh * 256;
        // coalesced tile read: 256 rows x 16 cols (f32), pitch-20 LDS
#pragma unroll
        for (int it = 0; it < 4; ++it) {
            int r = (tid >> 2) + it * 64;
            int c = (tid & 3) * 4;
            float4 v = *(const float4*)(W2 + (k0 + r) * HH + n0 + c);
            *(float4*)(T + r * 20 + c) = v;
        }
        __syncthreads();
#pragma unroll
        for (int p = 0; p < 2; ++p) {
            int ksl = p * 4 + wv;
            int kq  = ksl * 32 + q * 8;
            s16x8 o;
#pragma unroll
            for (int j = 0; j < 8; ++j) o[j] = (short)f2bf(T[(kq + j) * 20 + m16]);
            *(s16x8*)(W2f + nt * 8192 + (k0 / 32 + ksl) * 512 + lane * 8) = o;
        }
    } else if (bid < 136) {
        // ================= W3f transpose blocks =================
        const int ot = (bid - 128) >> 1, kh = (bid - 128) & 1;
        const int o0 = ot * 16, k0 = kh * 256;
#pragma unroll
        for (int it = 0; it < 4; ++it) {
            int r = (tid >> 2) + it * 64;
            int c = (tid & 3) * 4;
            float4 v = *(const float4*)(W3 + (k0 + r) * DD + o0 + c);
            *(float4*)(T + r * 20 + c) = v;
        }
        __syncthreads();
#pragma unroll
        for (int p = 0; p < 2; ++p) {
            int ksl = p * 4 + wv;
            int kq  = ksl * 32 + q * 8;
            s16x8 o;
#pragma unroll
            for (int j = 0; j < 8; ++j) o[j] = (short)f2bf(T[(kq + j) * 20 + m16]);
            *(s16x8*)(W3f + ot * 8192 + (k0 / 32 + ksl) * 512 + lane * 8) = o;
        }
    } else {
        for (int n = tid; n < HH; n += 256)
            z0[n] = b1[n] + t[0] * W1[n];
    }
}

// =======================================================================
// cnf_main: 256 blocks x 1024 threads (16 waves)
// =======================================================================
__global__ __launch_bounds__(TPB) void cnf_main(
    const float* __restrict__ x,  const u16* __restrict__ ws16,
    const float* __restrict__ z0, const float* __restrict__ b2,
    const float* __restrict__ b3, float* __restrict__ out)
{
    __shared__ u16 h1s[MROWS * LP];
    __shared__ u16 h2s[MROWS * LP];
    __shared__ u16 d2s[MROWS * LP];     // low bytes double as xs before phase 2
    __shared__ float z0s[HH];
    __shared__ float b2s[HH];
    __shared__ float b3s[DD];
    __shared__ float divacc[16][MROWS];

    const u16* Ef  = ws16 + OFF_EF;
    const u16* W2f = ws16 + OFF_W2F;
    const u16* W1f = ws16 + OFF_W1F;
    const u16* W3f = ws16 + OFF_W3F;

    const int tid  = threadIdx.x;
    const int lane = tid & 63;
    const int w    = tid >> 6;        // 16 waves
    const int m16  = lane & 15;
    const int q    = lane >> 4;
    const int kq   = q * 8;
    const int n1   = w * 32;          // wave's 32-col slice (phases 1,2,4)
    const int r0   = blockIdx.x * MROWS;

    u16* xs = d2s;                    // overlap: xs dead after phase 1

    // ---- hoisted global prefetch: phase-1 W1f frags + phase-2 initial W2f frags ----
    s16x8 p1b[2][2];
#pragma unroll
    for (int ct = 0; ct < 2; ++ct) {
        const u16* bb = W1f + (w * 2 + ct) * 1024 + lane * 8;
        p1b[ct][0] = *(const s16x8*)(bb);
        p1b[ct][1] = *(const s16x8*)(bb + 512);
    }
    const u16* w2bp0 = W2f + (2 * w + 0) * 8192 + lane * 8;
    const u16* w2bp1 = W2f + (2 * w + 1) * 8192 + lane * 8;
    s16x8 bA0 = *(const s16x8*)(w2bp0);
    s16x8 bA1 = *(const s16x8*)(w2bp1);
    s16x8 bB0 = *(const s16x8*)(w2bp0 + 512);
    s16x8 bB1 = *(const s16x8*)(w2bp1 + 512);

    // ---- stage ----
    for (int idx = tid; idx < MROWS * DD; idx += TPB) {
        int r = idx >> 6, c = idx & 63;
        xs[r * 72 + c] = f2bf(x[(r0 + r) * (DD + 1) + c]);
    }
    if (tid < HH) { z0s[tid] = z0[tid]; b2s[tid] = b2[tid]; }
    if (tid < DD) b3s[tid] = b3[tid];
    __syncthreads();

    float d1reg[2][2][4];             // d1 = 1-h1^2, kept in regs for phase 4

    // ---- phase 1: h1 = tanh([t,x]@W1 + z0), K=64 ----
    {
        s16x8 xa[2][2];
#pragma unroll
        for (int rt = 0; rt < 2; ++rt)
#pragma unroll
            for (int h = 0; h < 2; ++h)
                xa[rt][h] = *(const s16x8*)(xs + (rt * 16 + m16) * 72 + h * 32 + kq);
#pragma unroll
        for (int ct = 0; ct < 2; ++ct) {
            int col = n1 + ct * 16 + m16;
#pragma unroll
            for (int rt = 0; rt < 2; ++rt) {
                f32x4 c = {0.f, 0.f, 0.f, 0.f};
                c = MFMA16(xa[rt][0], p1b[ct][0], c);
                c = MFMA16(xa[rt][1], p1b[ct][1], c);
#pragma unroll
                for (int i = 0; i < 4; ++i) {
                    float hv = fast_tanh(c[i] + z0s[col]);
                    h1s[(rt * 16 + 4 * q + i) * LP + col] = f2bf(hv);
                    d1reg[rt][ct][i] = 1.0f - hv * hv;
                }
            }
        }
    }
    __syncthreads();

    // ---- phase 2: h2 = tanh(h1@W2 + b2); d2 -> d2s ----
    {
        f32x4 a00={0,0,0,0}, a01={0,0,0,0}, a10={0,0,0,0}, a11={0,0,0,0};
        const u16* ap0 = h1s + m16 * LP + kq;
        const u16* ap1 = h1s + (16 + m16) * LP + kq;
#pragma unroll 2
        for (int ks = 0; ks < 16; ks += 2) {
            int k2 = (ks + 2) & 15, k3 = (ks + 3) & 15;
            s16x8 nA0 = *(const s16x8*)(w2bp0 + k2 * 512);
            s16x8 nA1 = *(const s16x8*)(w2bp1 + k2 * 512);
            s16x8 f0  = *(const s16x8*)(ap0 + ks * 32);
            s16x8 f1  = *(const s16x8*)(ap1 + ks * 32);
            a00 = MFMA16(f0, bA0, a00);
            a10 = MFMA16(f1, bA0, a10);
            a01 = MFMA16(f0, bA1, a01);
            a11 = MFMA16(f1, bA1, a11);
            s16x8 nB0 = *(const s16x8*)(w2bp0 + k3 * 512);
            s16x8 nB1 = *(const s16x8*)(w2bp1 + k3 * 512);
            s16x8 f2  = *(const s16x8*)(ap0 + ks * 32 + 32);
            s16x8 f3  = *(const s16x8*)(ap1 + ks * 32 + 32);
            a00 = MFMA16(f2, bB0, a00);
            a10 = MFMA16(f3, bB0, a10);
            a01 = MFMA16(f2, bB1, a01);
            a11 = MFMA16(f3, bB1, a11);
            bA0 = nA0; bA1 = nA1; bB0 = nB0; bB1 = nB1;
        }
        f32x4 acc[2][2] = {{a00, a01}, {a10, a11}};
#pragma unroll
        for (int rt = 0; rt < 2; ++rt)
#pragma unroll
            for (int ct = 0; ct < 2; ++ct) {
                int col = n1 + ct * 16 + m16;
#pragma unroll
                for (int i = 0; i < 4; ++i) {
                    int row = rt * 16 + 4 * q + i;
                    float hv = fast_tanh(acc[rt][ct][i] + b2s[col]);
                    h2s[row * LP + col] = f2bf(hv);
                    d2s[row * LP + col] = f2bf(1.0f - hv * hv);
                }
            }
    }
    __syncthreads();

    // ---- phase 3 (waves 0..7): dx = h2@W3 + b3 ----
    if (w < 8) {
        const int rowt = w >> 2, ot = w & 3;
        f32x4 c3 = {0.f, 0.f, 0.f, 0.f};
        const u16* ap = h2s + (rowt * 16 + m16) * LP + kq;
        const u16* bp = W3f + ot * 8192 + lane * 8;
#pragma unroll 4
        for (int ks = 0; ks < 16; ++ks)
            c3 = MFMA16(*(const s16x8*)(ap + ks * 32),
                        *(const s16x8*)(bp + ks * 512), c3);
        int o = ot * 16 + m16;
#pragma unroll
        for (int i = 0; i < 4; ++i)
            out[(r0 + rowt * 16 + 4 * q + i) * (DD + 1) + o] = c3[i] + b3s[o];
    }

    // ---- phase 4 (all 16 waves): M = d2@Ef; div = sum d1 .* M ----
    {
        f32x4 a00={0,0,0,0}, a01={0,0,0,0}, a10={0,0,0,0}, a11={0,0,0,0};
        const u16* ap0 = d2s + m16 * LP + kq;
        const u16* ap1 = d2s + (16 + m16) * LP + kq;
        const u16* bp0 = Ef + (2 * w + 0) * 8192 + lane * 8;
        const u16* bp1 = Ef + (2 * w + 1) * 8192 + lane * 8;
        s16x8 cA0 = *(const s16x8*)(bp0);
        s16x8 cA1 = *(const s16x8*)(bp1);
        s16x8 cB0 = *(const s16x8*)(bp0 + 512);
        s16x8 cB1 = *(const s16x8*)(bp1 + 512);
#pragma unroll 2
        for (int ks = 0; ks < 16; ks += 2) {
            int k2 = (ks + 2) & 15, k3 = (ks + 3) & 15;
            s16x8 nA0 = *(const s16x8*)(bp0 + k2 * 512);
            s16x8 nA1 = *(const s16x8*)(bp1 + k2 * 512);
            s16x8 f0  = *(const s16x8*)(ap0 + ks * 32);
            s16x8 f1  = *(const s16x8*)(ap1 + ks * 32);
            a00 = MFMA16(f0, cA0, a00);
            a10 = MFMA16(f1, cA0, a10);
            a01 = MFMA16(f0, cA1, a01);
            a11 = MFMA16(f1, cA1, a11);
            s16x8 nB0 = *(const s16x8*)(bp0 + k3 * 512);
            s16x8 nB1 = *(const s16x8*)(bp1 + k3 * 512);
            s16x8 f2  = *(const s16x8*)(ap0 + ks * 32 + 32);
            s16x8 f3  = *(const s16x8*)(ap1 + ks * 32 + 32);
            a00 = MFMA16(f2, cB0, a00);
            a10 = MFMA16(f3, cB0, a10);
            a01 = MFMA16(f2, cB1, a01);
            a11 = MFMA16(f3, cB1, a11);
            cA0 = nA0; cA1 = nA1; cB0 = nB0; cB1 = nB1;
        }
        f32x4 acc[2][2] = {{a00, a01}, {a10, a11}};
#pragma unroll
        for (int rt = 0; rt < 2; ++rt)
#pragma unroll
            for (int i = 0; i < 4; ++i) {
                float v = d1reg[rt][0][i] * acc[rt][0][i]
                        + d1reg[rt][1][i] * acc[rt][1][i];
                v += __shfl_xor(v, 1, 64);
                v += __shfl_xor(v, 2, 64);
                v += __shfl_xor(v, 4, 64);
                v += __shfl_xor(v, 8, 64);
                if (m16 == 0) divacc[w][rt * 16 + 4 * q + i] = v;
            }
    }
    __syncthreads();

    if (tid < MROWS) {
        float s = 0.0f;
#pragma unroll
        for (int ww = 0; ww < 16; ++ww) s += divacc[ww][tid];
        out[(r0 + tid) * (DD + 1) + DD] = s;
    }
}

extern "C" void kernel_launch(void* const* d_in, const int* in_sizes, int n_in,
                              void* d_out, int out_size, void* d_ws, size_t ws_size,
                              hipStream_t stream) {
    const float* t  = (const float*)d_in[0];
    const float* x  = (const float*)d_in[1];
    const float* W1 = (const float*)d_in[2];
    const float* b1 = (const float*)d_in[3];
    const float* W2 = (const float*)d_in[4];
    const float* b2 = (const float*)d_in[5];
    const float* W3 = (const float*)d_in[6];
    const float* b3 = (const float*)d_in[7];
    float* out = (float*)d_out;

    u16*   ws16 = (u16*)d_ws;
    float* z0   = (float*)((char*)d_ws + OFF_Z0B);

    precompute<<<137, 256, 0, stream>>>(t, W1, b1, W2, W3, ws16, z0);
    cnf_main<<<8192 / MROWS, TPB, 0, stream>>>(x, ws16, z0, b2, b3, out);
}

// Round 5
// 93.159 us; speedup vs baseline: 2.9689x; 1.0192x over previous
//
#include <hip/hip_runtime.h>

#define HH 512
#define DD 64
#define MROWS 32
#define TPB 1024
#define LP 520            // u16 pitch for 32x512 LDS tiles

typedef unsigned short u16;
typedef short s16x8 __attribute__((ext_vector_type(8)));   // 8 bf16 = 4 VGPRs
typedef float f32x4 __attribute__((ext_vector_type(4)));

#define MFMA16(A,B,C) __builtin_amdgcn_mfma_f32_16x16x32_bf16((A),(B),(C),0,0,0)

// ---- workspace layout (u16 element offsets), fragment-linear:
//   addr = ntile*16*K + ks*512 + lane*8 ; value[j] = M[k = ks*32+(lane>>4)*8+j][n = nt*16+(lane&15)]
#define OFF_EF   0
#define OFF_W2F  (HH*HH)
#define OFF_W1F  (2*HH*HH)
#define OFF_W3F  (2*HH*HH + HH*DD)
#define OFF_Z0B  ((2*HH*HH + 2*HH*DD)*2)   // byte offset of z0 (f32[512])

__device__ __forceinline__ u16 f2bf(float f) {
    unsigned u = __builtin_bit_cast(unsigned, f);
    u += 0x7fffu + ((u >> 16) & 1u);
    return (u16)(u >> 16);
}
__device__ __forceinline__ float bf2f(u16 h) {
    return __builtin_bit_cast(float, (unsigned)h << 16);
}
__device__ __forceinline__ float fast_tanh(float x) {
    float e = __expf(2.0f * x);
    return 1.0f - 2.0f * __builtin_amdgcn_rcpf(e + 1.0f);
}

// =======================================================================
// precompute: 137 blocks x 256 threads (unchanged from R4 — ~3-5 us)
// =======================================================================
__global__ __launch_bounds__(256) void precompute(
    const float* __restrict__ t,  const float* __restrict__ W1,
    const float* __restrict__ b1, const float* __restrict__ W2,
    const float* __restrict__ W3, u16* __restrict__ ws16, float* __restrict__ z0)
{
    __shared__ float T[16 * 264 > 256 * 20 ? 16 * 264 : 256 * 20];
    u16* Ef  = ws16 + OFF_EF;
    u16* W2f = ws16 + OFF_W2F;
    u16* W1f = ws16 + OFF_W1F;
    u16* W3f = ws16 + OFF_W3F;

    const int bid = blockIdx.x, tid = threadIdx.x;
    const int lane = tid & 63, wv = tid >> 6;
    const int m16 = lane & 15, q = lane >> 4;

    if (bid < 64) {
        const int nt = bid >> 1, bh = bid & 1;
        const int a0 = nt * 16, b0 = bh * 256;
        s16x8 afh[2], afl[2];
#pragma unroll
        for (int h = 0; h < 2; ++h)
#pragma unroll
            for (int j = 0; j < 8; ++j) {
                int i = h * 32 + q * 8 + j;
                float v = W1[(1 + i) * HH + a0 + m16];
                u16 hi = f2bf(v);
                afh[h][j] = (short)hi;
                afl[h][j] = (short)f2bf(v - bf2f(hi));
            }
#pragma unroll
        for (int bt = 0; bt < 4; ++bt) {
            int bl = wv * 64 + bt * 16;
            s16x8 bfh[2], bfl[2];
#pragma unroll
            for (int h = 0; h < 2; ++h) {
                const float* src = W3 + (b0 + bl + m16) * DD + h * 32 + q * 8;
                float4 p0 = *(const float4*)(src);
                float4 p1 = *(const float4*)(src + 4);
                float vv[8] = {p0.x,p0.y,p0.z,p0.w,p1.x,p1.y,p1.z,p1.w};
#pragma unroll
                for (int j = 0; j < 8; ++j) {
                    u16 hi = f2bf(vv[j]);
                    bfh[h][j] = (short)hi;
                    bfl[h][j] = (short)f2bf(vv[j] - bf2f(hi));
                }
            }
            f32x4 c = {0.f, 0.f, 0.f, 0.f};
#pragma unroll
            for (int h = 0; h < 2; ++h) {
                c = MFMA16(afh[h], bfh[h], c);
                c = MFMA16(afh[h], bfl[h], c);
                c = MFMA16(afl[h], bfh[h], c);
            }
#pragma unroll
            for (int r = 0; r < 4; ++r)
                T[(4 * q + r) * 264 + bl + m16] = c[r];
        }
        __syncthreads();
#pragma unroll
        for (int p = 0; p < 2; ++p) {
            int ksl = p * 4 + wv;
            int al  = m16;
            int blc = ksl * 32 + q * 8;
            const float* w2p = W2 + (a0 + al) * HH + b0 + blc;
            float4 wa = *(const float4*)(w2p), wb = *(const float4*)(w2p + 4);
            const float* glp = T + al * 264 + blc;
            s16x8 o;
            o[0]=(short)f2bf(wa.x*glp[0]); o[1]=(short)f2bf(wa.y*glp[1]);
            o[2]=(short)f2bf(wa.z*glp[2]); o[3]=(short)f2bf(wa.w*glp[3]);
            o[4]=(short)f2bf(wb.x*glp[4]); o[5]=(short)f2bf(wb.y*glp[5]);
            o[6]=(short)f2bf(wb.z*glp[6]); o[7]=(short)f2bf(wb.w*glp[7]);
            *(s16x8*)(Ef + nt * 8192 + (b0 / 32 + ksl) * 512 + lane * 8) = o;
        }
        if (bh == 0 && tid < 128) {
            int ks = tid >> 6, ln = tid & 63;
            int n  = nt * 16 + (ln & 15);
            int k0 = ks * 32 + (ln >> 4) * 8;
            s16x8 o;
#pragma unroll
            for (int j = 0; j < 8; ++j) o[j] = (short)f2bf(W1[(1 + k0 + j) * HH + n]);
            *(s16x8*)(W1f + nt * 1024 + ks * 512 + ln * 8) = o;
        }
    } else if (bid < 128) {
        const int nt = (bid - 64) >> 1, kh = (bid - 64) & 1;
        const int n0 = nt * 16, k0 = kh * 256;
#pragma unroll
        for (int it = 0; it < 4; ++it) {
            int r = (tid >> 2) + it * 64;
            int c = (tid & 3) * 4;
            float4 v = *(const float4*)(W2 + (k0 + r) * HH + n0 + c);
            *(float4*)(T + r * 20 + c) = v;
        }
        __syncthreads();
#pragma unroll
        for (int p = 0; p < 2; ++p) {
            int ksl = p * 4 + wv;
            int kq  = ksl * 32 + q * 8;
            s16x8 o;
#pragma unroll
            for (int j = 0; j < 8; ++j) o[j] = (short)f2bf(T[(kq + j) * 20 + m16]);
            *(s16x8*)(W2f + nt * 8192 + (k0 / 32 + ksl) * 512 + lane * 8) = o;
        }
    } else if (bid < 136) {
        const int ot = (bid - 128) >> 1, kh = (bid - 128) & 1;
        const int o0 = ot * 16, k0 = kh * 256;
#pragma unroll
        for (int it = 0; it < 4; ++it) {
            int r = (tid >> 2) + it * 64;
            int c = (tid & 3) * 4;
            float4 v = *(const float4*)(W3 + (k0 + r) * DD + o0 + c);
            *(float4*)(T + r * 20 + c) = v;
        }
        __syncthreads();
#pragma unroll
        for (int p = 0; p < 2; ++p) {
            int ksl = p * 4 + wv;
            int kq  = ksl * 32 + q * 8;
            s16x8 o;
#pragma unroll
            for (int j = 0; j < 8; ++j) o[j] = (short)f2bf(T[(kq + j) * 20 + m16]);
            *(s16x8*)(W3f + ot * 8192 + (k0 / 32 + ksl) * 512 + lane * 8) = o;
        }
    } else {
        for (int n = tid; n < HH; n += 256)
            z0[n] = b1[n] + t[0] * W1[n];
    }
}

// =======================================================================
// cnf_main: 256 blocks x 1024 threads — deep-rotation pipelined
// =======================================================================
__global__ __launch_bounds__(TPB) void cnf_main(
    const float* __restrict__ x,  const u16* __restrict__ ws16,
    const float* __restrict__ z0, const float* __restrict__ b2,
    const float* __restrict__ b3, float* __restrict__ out)
{
    __shared__ u16 h1s[MROWS * LP];
    __shared__ u16 h2s[MROWS * LP];
    __shared__ u16 d2s[MROWS * LP];     // low bytes double as xs before phase 2
    __shared__ float z0s[HH];
    __shared__ float b2s[HH];
    __shared__ float b3s[DD];
    __shared__ float divacc[16][MROWS];

    const u16* Ef  = ws16 + OFF_EF;
    const u16* W2f = ws16 + OFF_W2F;
    const u16* W1f = ws16 + OFF_W1F;
    const u16* W3f = ws16 + OFF_W3F;

    const int tid  = threadIdx.x;
    const int lane = tid & 63;
    const int w    = tid >> 6;        // 16 waves
    const int m16  = lane & 15;
    const int q    = lane >> 4;
    const int kq   = q * 8;
    const int n1   = w * 32;          // wave's 32-col slice (phases 1,2,4)
    const int r0   = blockIdx.x * MROWS;

    u16* xs = d2s;                    // overlap: xs dead after phase 1

    // ---- top-of-kernel global prefetch: W1f frags + phase-2 first 4 k-steps ----
    s16x8 p1b[2][2];
#pragma unroll
    for (int ct = 0; ct < 2; ++ct) {
        const u16* bb = W1f + (w * 2 + ct) * 1024 + lane * 8;
        p1b[ct][0] = *(const s16x8*)(bb);
        p1b[ct][1] = *(const s16x8*)(bb + 512);
    }
    const u16* w2bp0 = W2f + (2 * w + 0) * 8192 + lane * 8;
    const u16* w2bp1 = W2f + (2 * w + 1) * 8192 + lane * 8;
    s16x8 B0[4], B1[4];
#pragma unroll
    for (int k = 0; k < 4; ++k) {
        B0[k] = *(const s16x8*)(w2bp0 + k * 512);
        B1[k] = *(const s16x8*)(w2bp1 + k * 512);
    }

    // ---- stage ----
    for (int idx = tid; idx < MROWS * DD; idx += TPB) {
        int r = idx >> 6, c = idx & 63;
        xs[r * 72 + c] = f2bf(x[(r0 + r) * (DD + 1) + c]);
    }
    if (tid < HH) { z0s[tid] = z0[tid]; b2s[tid] = b2[tid]; }
    if (tid < DD) b3s[tid] = b3[tid];
    __syncthreads();

    float d1reg[2][2][4];             // d1 = 1-h1^2, kept in regs for phase 4

    // ---- phase 1: h1 = tanh([t,x]@W1 + z0), K=64 ----
    {
        s16x8 xa[2][2];
#pragma unroll
        for (int rt = 0; rt < 2; ++rt)
#pragma unroll
            for (int h = 0; h < 2; ++h)
                xa[rt][h] = *(const s16x8*)(xs + (rt * 16 + m16) * 72 + h * 32 + kq);
#pragma unroll
        for (int ct = 0; ct < 2; ++ct) {
            int col = n1 + ct * 16 + m16;
#pragma unroll
            for (int rt = 0; rt < 2; ++rt) {
                f32x4 c = {0.f, 0.f, 0.f, 0.f};
                c = MFMA16(xa[rt][0], p1b[ct][0], c);
                c = MFMA16(xa[rt][1], p1b[ct][1], c);
#pragma unroll
                for (int i = 0; i < 4; ++i) {
                    float hv = fast_tanh(c[i] + z0s[col]);
                    h1s[(rt * 16 + 4 * q + i) * LP + col] = f2bf(hv);
                    d1reg[rt][ct][i] = 1.0f - hv * hv;
                }
            }
        }
    }
    __syncthreads();

    // ---- phase 2: h2 = tanh(h1@W2 + b2), 4-deep rotating B prefetch ----
    f32x4 a00={0,0,0,0}, a01={0,0,0,0}, a10={0,0,0,0}, a11={0,0,0,0};
    {
        const u16* ap0 = h1s + m16 * LP + kq;
        const u16* ap1 = h1s + (16 + m16) * LP + kq;
#pragma unroll
        for (int ks = 0; ks < 16; ++ks) {
            s16x8 f0 = *(const s16x8*)(ap0 + ks * 32);
            s16x8 f1 = *(const s16x8*)(ap1 + ks * 32);
            const int sl = ks & 3;
            a00 = MFMA16(f0, B0[sl], a00);
            a10 = MFMA16(f1, B0[sl], a10);
            a01 = MFMA16(f0, B1[sl], a01);
            a11 = MFMA16(f1, B1[sl], a11);
            if (ks < 12) {
                B0[sl] = *(const s16x8*)(w2bp0 + (ks + 4) * 512);
                B1[sl] = *(const s16x8*)(w2bp1 + (ks + 4) * 512);
            }
        }
    }

    // ---- issue phase-4 Ef preloads (depth 2) before epilogue/barrier ----
    const u16* efp0 = Ef + (2 * w + 0) * 8192 + lane * 8;
    const u16* efp1 = Ef + (2 * w + 1) * 8192 + lane * 8;
    s16x8 E0[4], E1[4];
#pragma unroll
    for (int k = 0; k < 2; ++k) {
        E0[k] = *(const s16x8*)(efp0 + k * 512);
        E1[k] = *(const s16x8*)(efp1 + k * 512);
    }

    // ---- phase-2 epilogue: tanh -> h2s, d2 -> d2s ----
    {
        f32x4 acc[2][2] = {{a00, a01}, {a10, a11}};
#pragma unroll
        for (int rt = 0; rt < 2; ++rt)
#pragma unroll
            for (int ct = 0; ct < 2; ++ct) {
                int col = n1 + ct * 16 + m16;
#pragma unroll
                for (int i = 0; i < 4; ++i) {
                    int row = rt * 16 + 4 * q + i;
                    float hv = fast_tanh(acc[rt][ct][i] + b2s[col]);
                    h2s[row * LP + col] = f2bf(hv);
                    d2s[row * LP + col] = f2bf(1.0f - hv * hv);
                }
            }
    }
    __syncthreads();

    // ---- phase 3 (waves 0..7): dx = h2@W3 + b3, 4-deep rotation ----
    if (w < 8) {
        const int rowt = w >> 2, ot = w & 3;
        const u16* ap = h2s + (rowt * 16 + m16) * LP + kq;
        const u16* bp = W3f + ot * 8192 + lane * 8;
        s16x8 W3r[4];
#pragma unroll
        for (int k = 0; k < 4; ++k) W3r[k] = *(const s16x8*)(bp + k * 512);
        f32x4 cA = {0.f,0.f,0.f,0.f}, cB = {0.f,0.f,0.f,0.f};
#pragma unroll
        for (int ks = 0; ks < 16; ++ks) {
            s16x8 f = *(const s16x8*)(ap + ks * 32);
            const int sl = ks & 3;
            if (ks & 1) cB = MFMA16(f, W3r[sl], cB);
            else        cA = MFMA16(f, W3r[sl], cA);
            if (ks < 12) W3r[sl] = *(const s16x8*)(bp + (ks + 4) * 512);
        }
        f32x4 c3 = cA + cB;
        int o = ot * 16 + m16;
#pragma unroll
        for (int i = 0; i < 4; ++i)
            out[(r0 + rowt * 16 + 4 * q + i) * (DD + 1) + o] = c3[i] + b3s[o];
    }

    // ---- phase 4 (all 16 waves): M = d2@Ef; div = sum d1 .* M ----
    {
        f32x4 g00={0,0,0,0}, g01={0,0,0,0}, g10={0,0,0,0}, g11={0,0,0,0};
        const u16* ap0 = d2s + m16 * LP + kq;
        const u16* ap1 = d2s + (16 + m16) * LP + kq;
#pragma unroll
        for (int ks = 0; ks < 16; ++ks) {
            s16x8 f0 = *(const s16x8*)(ap0 + ks * 32);
            s16x8 f1 = *(const s16x8*)(ap1 + ks * 32);
            const int sl = ks & 3;
            g00 = MFMA16(f0, E0[sl], g00);
            g10 = MFMA16(f1, E0[sl], g10);
            g01 = MFMA16(f0, E1[sl], g01);
            g11 = MFMA16(f1, E1[sl], g11);
            if (ks < 14) {
                const int dl = (ks + 2) & 3;
                E0[dl] = *(const s16x8*)(efp0 + (ks + 2) * 512);
                E1[dl] = *(const s16x8*)(efp1 + (ks + 2) * 512);
            }
        }
        f32x4 acc[2][2] = {{g00, g01}, {g10, g11}};
#pragma unroll
        for (int rt = 0; rt < 2; ++rt)
#pragma unroll
            for (int i = 0; i < 4; ++i) {
                float v = d1reg[rt][0][i] * acc[rt][0][i]
                        + d1reg[rt][1][i] * acc[rt][1][i];
                v += __shfl_xor(v, 1, 64);
                v += __shfl_xor(v, 2, 64);
                v += __shfl_xor(v, 4, 64);
                v += __shfl_xor(v, 8, 64);
                if (m16 == 0) divacc[w][rt * 16 + 4 * q + i] = v;
            }
    }
    __syncthreads();

    if (tid < MROWS) {
        float s = 0.0f;
#pragma unroll
        for (int ww = 0; ww < 16; ++ww) s += divacc[ww][tid];
        out[(r0 + tid) * (DD + 1) + DD] = s;
    }
}

extern "C" void kernel_launch(void* const* d_in, const int* in_sizes, int n_in,
                              void* d_out, int out_size, void* d_ws, size_t ws_size,
                              hipStream_t stream) {
    const float* t  = (const float*)d_in[0];
    const float* x  = (const float*)d_in[1];
    const float* W1 = (const float*)d_in[2];
    const float* b1 = (const float*)d_in[3];
    const float* W2 = (const float*)d_in[4];
    const float* b2 = (const float*)d_in[5];
    const float* W3 = (const float*)d_in[6];
    const float* b3 = (const float*)d_in[7];
    float* out = (float*)d_out;

    u16*   ws16 = (u16*)d_ws;
    float* z0   = (float*)((char*)d_ws + OFF_Z0B);

    precompute<<<137, 256, 0, stream>>>(t, W1, b1, W2, W3, ws16, z0);
    cnf_main<<<8192 / MROWS, TPB, 0, stream>>>(x, ws16, z0, b2, b3, out);
}